// Round 1
// baseline (350.002 us; speedup 1.0000x reference)
//
#include <hip/hip_runtime.h>

// SpatialTransformer: out[i,j,k,c] = trilinear(vol[0], (i,j,k) + trf[0,i,j,k,:])
// vol: [2,160,192,224,2] f32 (only batch 0 used)
// trf: [2,160,192,224,3] f32 (only batch 0 used)
// out: [160,192,224,2] f32

constexpr int D0 = 160, D1 = 192, D2 = 224;
constexpr int NVOX = D0 * D1 * D2;

__global__ __launch_bounds__(256) void st_trilinear_kernel(
    const float* __restrict__ vol,   // [D0,D1,D2,2]
    const float* __restrict__ trf,   // [D0,D1,D2,3]
    float2* __restrict__ out)        // [D0,D1,D2,2] as float2
{
    int v = blockIdx.x * blockDim.x + threadIdx.x;
    if (v >= NVOX) return;

    int k = v % D2;
    int t = v / D2;
    int j = t % D1;
    int i = t / D1;

    // dense shift
    float s0 = trf[3 * v + 0];
    float s1 = trf[3 * v + 1];
    float s2 = trf[3 * v + 2];

    // absolute sample location, clamped into domain (matches jnp.clip order)
    float l0 = fminf(fmaxf((float)i + s0, 0.0f), (float)(D0 - 1));
    float l1 = fminf(fmaxf((float)j + s1, 0.0f), (float)(D1 - 1));
    float l2 = fminf(fmaxf((float)k + s2, 0.0f), (float)(D2 - 1));

    // corner indices: loc0 = floor(loc) (already in [0,max]); loc1 = min(loc0+1, max)
    float f0 = floorf(l0), f1 = floorf(l1), f2 = floorf(l2);
    float g0 = fminf(f0 + 1.0f, (float)(D0 - 1));
    float g1 = fminf(f1 + 1.0f, (float)(D1 - 1));
    float g2 = fminf(f2 + 1.0f, (float)(D2 - 1));

    // corner-0 weight = loc1 - loc; corner-1 weight = 1 - that (reference math)
    float w0a = g0 - l0, w1a = g1 - l1, w2a = g2 - l2;
    float w0b = 1.0f - w0a, w1b = 1.0f - w1a, w2b = 1.0f - w2a;

    int i0 = (int)f0, j0 = (int)f1, k0 = (int)f2;
    int i1 = (int)g0, j1 = (int)g1, k1 = (int)g2;

    const float2* __restrict__ vol2 = (const float2*)vol;
    int r0 = i0 * (D1 * D2), r1 = i1 * (D1 * D2);
    int c0 = j0 * D2,        c1 = j1 * D2;

    float2 p;
    float accx = 0.0f, accy = 0.0f;
    float w;

    w = w0a * w1a * w2a; p = vol2[r0 + c0 + k0]; accx += w * p.x; accy += w * p.y;
    w = w0a * w1a * w2b; p = vol2[r0 + c0 + k1]; accx += w * p.x; accy += w * p.y;
    w = w0a * w1b * w2a; p = vol2[r0 + c1 + k0]; accx += w * p.x; accy += w * p.y;
    w = w0a * w1b * w2b; p = vol2[r0 + c1 + k1]; accx += w * p.x; accy += w * p.y;
    w = w0b * w1a * w2a; p = vol2[r1 + c0 + k0]; accx += w * p.x; accy += w * p.y;
    w = w0b * w1a * w2b; p = vol2[r1 + c0 + k1]; accx += w * p.x; accy += w * p.y;
    w = w0b * w1b * w2a; p = vol2[r1 + c1 + k0]; accx += w * p.x; accy += w * p.y;
    w = w0b * w1b * w2b; p = vol2[r1 + c1 + k1]; accx += w * p.x; accy += w * p.y;

    out[v] = make_float2(accx, accy);
}

extern "C" void kernel_launch(void* const* d_in, const int* in_sizes, int n_in,
                              void* d_out, int out_size, void* d_ws, size_t ws_size,
                              hipStream_t stream) {
    const float* vol = (const float*)d_in[0];  // [2,160,192,224,2]; batch 0 at offset 0
    const float* trf = (const float*)d_in[1];  // [2,160,192,224,3]; batch 0 at offset 0
    float2* out = (float2*)d_out;              // [160,192,224,2]

    int blocks = (NVOX + 255) / 256;
    st_trilinear_kernel<<<blocks, 256, 0, stream>>>(vol, trf, out);
}

// Round 2
// 345.713 us; speedup vs baseline: 1.0124x; 1.0124x over previous
//
#include <hip/hip_runtime.h>

// SpatialTransformer: out[i,j,k,c] = trilinear(vol[0], (i,j,k) + trf[0,i,j,k,:])
// vol: [2,160,192,224,2] f32 (batch 0 only), trf: [2,160,192,224,3] f32 (batch 0 only)
// out: [160,192,224,2] f32
//
// R1 analysis: 135us, vmem-instr issue bound (12 vmem/voxel = 1.00 instr/cyc/CU).
// R2: pair-merged z gathers (float4, 8B-aligned) + 2 voxels/thread -> 5.5 vmem/voxel.

constexpr int D0 = 160, D1 = 192, D2 = 224;
constexpr int NVOX = D0 * D1 * D2;
constexpr int NTHREADS = NVOX / 2;          // 3,440,640 ; /256 = 13440 blocks exact

// float4 with only-8B alignment guarantee (gfx950 dwordx4 needs just dword align)
typedef float float4u __attribute__((ext_vector_type(4), aligned(8)));

__device__ __forceinline__ float2 sample_one(const float2* __restrict__ vol2,
                                             int i, int j, int k,
                                             float s0, float s1, float s2)
{
    // absolute sample location, clamped (matches reference clip order)
    float l0 = fminf(fmaxf((float)i + s0, 0.0f), (float)(D0 - 1));
    float l1 = fminf(fmaxf((float)j + s1, 0.0f), (float)(D1 - 1));
    float l2 = fminf(fmaxf((float)k + s2, 0.0f), (float)(D2 - 1));

    float f0 = floorf(l0), f1 = floorf(l1), f2 = floorf(l2);
    float g0 = fminf(f0 + 1.0f, (float)(D0 - 1));
    float g1 = fminf(f1 + 1.0f, (float)(D1 - 1));
    float g2 = fminf(f2 + 1.0f, (float)(D2 - 1));

    float w0a = g0 - l0, w1a = g1 - l1, w2a = g2 - l2;
    float w0b = 1.0f - w0a, w1b = 1.0f - w1a, w2b = 1.0f - w2a;

    int i0 = (int)f0, j0 = (int)f1, k0 = (int)f2;
    int i1 = (int)g0, j1 = (int)g1;
    // pair base: when k0==D2-1, l2==D2-1 exactly => w2a==0, so reading (D2-2, D2-1)
    // with weights (w2a, w2b) still yields v[D2-1]. Branchless boundary.
    int kb = min(k0, D2 - 2);

    int r0 = i0 * (D1 * D2), r1 = i1 * (D1 * D2);
    int c0 = j0 * D2,        c1 = j1 * D2;

    float4u q00 = *(const float4u*)(vol2 + (r0 + c0 + kb));  // v[kb].xy, v[kb+1].xy
    float4u q01 = *(const float4u*)(vol2 + (r0 + c1 + kb));
    float4u q10 = *(const float4u*)(vol2 + (r1 + c0 + kb));
    float4u q11 = *(const float4u*)(vol2 + (r1 + c1 + kb));

    // z-lerp each corner pair
    float v00x = w2a * q00.x + w2b * q00.z, v00y = w2a * q00.y + w2b * q00.w;
    float v01x = w2a * q01.x + w2b * q01.z, v01y = w2a * q01.y + w2b * q01.w;
    float v10x = w2a * q10.x + w2b * q10.z, v10y = w2a * q10.y + w2b * q10.w;
    float v11x = w2a * q11.x + w2b * q11.z, v11y = w2a * q11.y + w2b * q11.w;

    // bilinear in (i,j)
    float waa = w0a * w1a, wab = w0a * w1b, wba = w0b * w1a, wbb = w0b * w1b;
    float2 r;
    r.x = waa * v00x + wab * v01x + wba * v10x + wbb * v11x;
    r.y = waa * v00y + wab * v01y + wba * v10y + wbb * v11y;
    return r;
}

__global__ __launch_bounds__(256) void st_trilinear2_kernel(
    const float* __restrict__ vol,   // [D0,D1,D2,2]
    const float* __restrict__ trf,   // [D0,D1,D2,3]
    float4* __restrict__ out)        // [D0,D1,D2,2] viewed as float4 per voxel-pair
{
    int u = blockIdx.x * blockDim.x + threadIdx.x;   // one thread = 2 adjacent voxels (k even)
    if (u >= NTHREADS) return;

    int v0 = 2 * u;
    int k = v0 % D2;              // even; k+1 stays in the same row (D2 even)
    int t = v0 / D2;
    int j = t % D1;
    int i = t / D1;

    // 6 shift floats for the voxel pair: dwordx4 + dwordx2 (8B-aligned)
    const float* tp = trf + 6 * (long long)u;
    float4u T0 = *(const float4u*)tp;        // sA0 sA1 sA2 sB0
    float2  T1 = *(const float2*)(tp + 4);   // sB1 sB2

    const float2* vol2 = (const float2*)vol;
    float2 A = sample_one(vol2, i, j, k,     T0.x, T0.y, T0.z);
    float2 B = sample_one(vol2, i, j, k + 1, T0.w, T1.x, T1.y);

    float4 o;
    o.x = A.x; o.y = A.y; o.z = B.x; o.w = B.y;
    out[u] = o;                              // 16B aligned store
}

extern "C" void kernel_launch(void* const* d_in, const int* in_sizes, int n_in,
                              void* d_out, int out_size, void* d_ws, size_t ws_size,
                              hipStream_t stream) {
    const float* vol = (const float*)d_in[0];
    const float* trf = (const float*)d_in[1];
    float4* out = (float4*)d_out;

    int blocks = (NTHREADS + 255) / 256;
    st_trilinear2_kernel<<<blocks, 256, 0, stream>>>(vol, trf, out);
}

// Round 4
// 301.388 us; speedup vs baseline: 1.1613x; 1.1471x over previous
//
#include <hip/hip_runtime.h>

// SpatialTransformer: out[i,j,k,c] = trilinear(vol[0], (i,j,k) + trf[0,i,j,k,:])
// vol: [2,160,192,224,2] f32 (batch 0 only), trf: [2,160,192,224,3] f32 (batch 0 only)
// out: [160,192,224,2] f32
//
// R1: 135us flat-index.  R2: 131us pair-merged gathers -> not issue-bound.
// R3: 3D-tiled blocks (4x8x16 voxels) -> host core dump; only structural change
//     was the 3D grid. R4: identical tiling, 1D grid decoded in-kernel.

constexpr int D0 = 160, D1 = 192, D2 = 224;
constexpr int GT_K = D2 / 16;   // 14 tiles along k (16 voxels each)
constexpr int GT_J = D1 / 8;    // 24 tiles along j
constexpr int GT_I = D0 / 4;    // 40 tiles along i
constexpr int NBLOCKS = GT_K * GT_J * GT_I;  // 13440

// float4 with only-8B alignment guarantee
typedef float float4u __attribute__((ext_vector_type(4), aligned(8)));

__device__ __forceinline__ float2 sample_one(const float2* __restrict__ vol2,
                                             int i, int j, int k,
                                             float s0, float s1, float s2)
{
    float l0 = fminf(fmaxf((float)i + s0, 0.0f), (float)(D0 - 1));
    float l1 = fminf(fmaxf((float)j + s1, 0.0f), (float)(D1 - 1));
    float l2 = fminf(fmaxf((float)k + s2, 0.0f), (float)(D2 - 1));

    float f0 = floorf(l0), f1 = floorf(l1), f2 = floorf(l2);
    float g0 = fminf(f0 + 1.0f, (float)(D0 - 1));
    float g1 = fminf(f1 + 1.0f, (float)(D1 - 1));
    float g2 = fminf(f2 + 1.0f, (float)(D2 - 1));

    float w0a = g0 - l0, w1a = g1 - l1, w2a = g2 - l2;
    float w0b = 1.0f - w0a, w1b = 1.0f - w1a, w2b = 1.0f - w2a;

    int i0 = (int)f0, j0 = (int)f1, k0 = (int)f2;
    int i1 = (int)g0, j1 = (int)g1;
    // When k0==D2-1, w2a==0, so reading pair (D2-2, D2-1) is still exact.
    int kb = min(k0, D2 - 2);

    int r0 = i0 * (D1 * D2), r1 = i1 * (D1 * D2);
    int c0 = j0 * D2,        c1 = j1 * D2;

    float4u q00 = *(const float4u*)(vol2 + (r0 + c0 + kb));
    float4u q01 = *(const float4u*)(vol2 + (r0 + c1 + kb));
    float4u q10 = *(const float4u*)(vol2 + (r1 + c0 + kb));
    float4u q11 = *(const float4u*)(vol2 + (r1 + c1 + kb));

    float v00x = w2a * q00.x + w2b * q00.z, v00y = w2a * q00.y + w2b * q00.w;
    float v01x = w2a * q01.x + w2b * q01.z, v01y = w2a * q01.y + w2b * q01.w;
    float v10x = w2a * q10.x + w2b * q10.z, v10y = w2a * q10.y + w2b * q10.w;
    float v11x = w2a * q11.x + w2b * q11.z, v11y = w2a * q11.y + w2b * q11.w;

    float waa = w0a * w1a, wab = w0a * w1b, wba = w0b * w1a, wbb = w0b * w1b;
    float2 r;
    r.x = waa * v00x + wab * v01x + wba * v10x + wbb * v11x;
    r.y = waa * v00y + wab * v01y + wba * v10y + wbb * v11y;
    return r;
}

__global__ __launch_bounds__(256) void st_trilinear4_kernel(
    const float* __restrict__ vol,   // [D0,D1,D2,2]
    const float* __restrict__ trf,   // [D0,D1,D2,3]
    float4* __restrict__ out)        // voxel-pairs
{
    // decode flat block index -> 3D tile coords (k fastest)
    int b = blockIdx.x;
    int tk = b % GT_K;
    int tb = b / GT_K;
    int tj = tb % GT_J;
    int ti = tb / GT_J;

    int tid = threadIdx.x;
    int kp_l = tid & 7;          // k-pair within tile (0..7)
    int j_l  = (tid >> 3) & 7;   // 0..7
    int i_l  = tid >> 6;         // 0..3

    int i = ti * 4 + i_l;
    int j = tj * 8 + j_l;
    int k = (tk * 8 + kp_l) * 2;

    int v0 = (i * D1 + j) * D2 + k;      // even
    int u = v0 >> 1;                     // voxel-pair index (< 2^22, int ok)

    const float* tp = trf + 6 * (long long)u;
    float4u T0 = *(const float4u*)tp;      // sA0 sA1 sA2 sB0
    float2  T1 = *(const float2*)(tp + 4); // sB1 sB2

    const float2* vol2 = (const float2*)vol;
    float2 A = sample_one(vol2, i, j, k,     T0.x, T0.y, T0.z);
    float2 B = sample_one(vol2, i, j, k + 1, T0.w, T1.x, T1.y);

    float4 o;
    o.x = A.x; o.y = A.y; o.z = B.x; o.w = B.y;
    out[u] = o;
}

extern "C" void kernel_launch(void* const* d_in, const int* in_sizes, int n_in,
                              void* d_out, int out_size, void* d_ws, size_t ws_size,
                              hipStream_t stream) {
    const float* vol = (const float*)d_in[0];
    const float* trf = (const float*)d_in[1];
    float4* out = (float4*)d_out;

    st_trilinear4_kernel<<<NBLOCKS, 256, 0, stream>>>(vol, trf, out);
}